// Round 11
// baseline (334.243 us; speedup 1.0000x reference)
//
#include <hip/hip_runtime.h>
#include <cstdint>
#include <cstddef>

typedef short v8s __attribute__((ext_vector_type(8)));
typedef float v4f __attribute__((ext_vector_type(4)));
typedef float v16f __attribute__((ext_vector_type(16)));

__device__ inline float bs2f(short s) {
    return __uint_as_float(((unsigned int)(unsigned short)s) << 16);
}
__device__ inline short f2bs(float f) {
    unsigned int u = __float_as_uint(f);
    unsigned int r = (u + 0x7fffu + ((u >> 16) & 1u)) >> 16;  // RNE
    return (short)r;
}
// pack two f32 -> two truncated bf16 in one u32 (lo = a, hi = b)
__device__ inline unsigned pkbf(float a, float b) {
    return (__float_as_uint(a) >> 16) | (__float_as_uint(b) & 0xffff0000u);
}

#define MFMA(a, b, c) __builtin_amdgcn_mfma_f32_16x16x32_bf16((a), (b), (c), 0, 0, 0)
#define MFMA32(a, b, c) __builtin_amdgcn_mfma_f32_32x32x16_bf16((a), (b), (c), 0, 0, 0)

// async global->LDS, 16B per lane, LDS dest = wave-uniform base + lane*16
#define GLOAD_LDS16(g, l)                                                  \
    __builtin_amdgcn_global_load_lds(                                      \
        (const __attribute__((address_space(1))) void*)(g),                \
        (__attribute__((address_space(3))) void*)(l), 16, 0, 0)

// ---------------------------------------------------- fused preprocessing
__global__ __launch_bounds__(256) void prep(const float* __restrict__ x,
                                            short* __restrict__ xb,
                                            const float* __restrict__ Wq,
                                            const float* __restrict__ Wkv,
                                            const float* __restrict__ Wkr,
                                            const float* __restrict__ Wkn,
                                            const float* __restrict__ Wv,
                                            const float* __restrict__ Wo,
                                            short* __restrict__ WtA,
                                            short* __restrict__ WtB,
                                            short* __restrict__ Wot) {
    int blk = blockIdx.x;
    if (blk < 8192) {
        int i = (blk * 256 + threadIdx.x) * 4;
        float4 v = *(const float4*)(x + i);
        short r[4] = {f2bs(v.x), f2bs(v.y), f2bs(v.z), f2bs(v.w)};
        *(uint2*)(xb + i) = *(const uint2*)r;
        return;
    }
    blk -= 8192;
    const float* W;
    short* Wt;
    int K, N, bx, by;
    if (blk < 4096)      { W = Wq;  Wt = WtA;                      K = 2048; N = 2048; bx = blk & 63; by = blk >> 6; }
    else if (blk < 5120) { blk -= 4096; W = Wkv; Wt = WtA + (size_t)2048 * 2048; K = 2048; N = 512;  bx = blk & 15; by = blk >> 4; }
    else if (blk < 5632) { blk -= 5120; W = Wkr; Wt = WtB;                       K = 512;  N = 1024; bx = blk & 31; by = blk >> 5; }
    else if (blk < 6144) { blk -= 5632; W = Wkn; Wt = WtB + (size_t)1024 * 512;  K = 512;  N = 1024; bx = blk & 31; by = blk >> 5; }
    else if (blk < 7168) { blk -= 6144; W = Wv;  Wt = WtB + (size_t)2048 * 512;  K = 512;  N = 2048; bx = blk & 63; by = blk >> 6; }
    else                 { blk -= 7168; W = Wo;  Wt = Wot;                       K = 2048; N = 2048; bx = blk & 63; by = blk >> 6; }

    __shared__ float tile[32][33];
    const int tx = threadIdx.x & 31, ty = threadIdx.x >> 5;  // ty 0..7
    const int n0 = bx * 32, k0 = by * 32;
#pragma unroll
    for (int i = 0; i < 32; i += 8) tile[ty + i][tx] = W[(size_t)(k0 + ty + i) * N + n0 + tx];
    __syncthreads();
#pragma unroll
    for (int i = 0; i < 32; i += 8)
        Wt[(size_t)(n0 + ty + i) * K + k0 + tx] = f2bs(tile[tx][ty + i]);
}

// ----------------------------------------------------------------- GEMM B^T
// 2-phase single-barrier double-buffer (the 330.4us-measured config).
__global__ __launch_bounds__(256) void gemm_bt(const short* __restrict__ A,
                                               const short* __restrict__ Bt,
                                               void* __restrict__ C0,
                                               void* __restrict__ C1,
                                               void* __restrict__ C2,
                                               int M, int N, int K, int mode,
                                               const float* __restrict__ g,
                                               float scale) {
    __shared__ short As[2 * 128 * 32];
    __shared__ short Bs[2 * 128 * 32];
    const int tid = threadIdx.x;
    const int lane = tid & 63, wave = tid >> 6;
    const int l16 = lane & 15, quad = lane >> 4;
    const int wm = (wave >> 1) * 64, wn = (wave & 1) * 64;

    const int gx = gridDim.x;
    const int nwg = gx * gridDim.y;
    const int wg = blockIdx.y * gx + blockIdx.x;
    const int cpx = nwg >> 3;
    const int swz = (wg & 7) * cpx + (wg >> 3);
    const int m0 = (swz / gx) * 128, n0 = (swz % gx) * 128;

    const v4f VZ = {0.f, 0.f, 0.f, 0.f};
    v4f acc[4][4];
#pragma unroll
    for (int i = 0; i < 4; i++)
#pragma unroll
        for (int j = 0; j < 4; j++) acc[i][j] = VZ;

    const int r0 = wave * 32 + (lane >> 2);
    const int r1 = r0 + 16;
    const int c0 = ((lane & 3) ^ ((r0 >> 1) & 3)) * 8;
    const int c1 = ((lane & 3) ^ ((r1 >> 1) & 3)) * 8;
    const short* aSrc0 = A + (size_t)(m0 + r0) * K + c0;
    const short* aSrc1 = A + (size_t)(m0 + r1) * K + c1;
    const short* bSrc0 = Bt + (size_t)(n0 + r0) * K + c0;
    const short* bSrc1 = Bt + (size_t)(n0 + r1) * K + c1;
    const int la0 = (wave * 32) * 32, la1 = (wave * 32 + 16) * 32;

    // prologue: stage tile 0 into buffer 0
    GLOAD_LDS16(aSrc0, &As[la0]);
    GLOAD_LDS16(aSrc1, &As[la1]);
    GLOAD_LDS16(bSrc0, &Bs[la0]);
    GLOAD_LDS16(bSrc1, &Bs[la1]);

    int cur = 0;
    for (int kk = 0; kk < K; kk += 32) {
        __syncthreads();  // buf[cur] staged (vmcnt drain) + prev reads done
        __builtin_amdgcn_sched_barrier(0);
        if (kk + 32 < K) {
            const int lo = (cur ^ 1) * 4096;
            GLOAD_LDS16(aSrc0 + kk + 32, &As[lo + la0]);
            GLOAD_LDS16(aSrc1 + kk + 32, &As[lo + la1]);
            GLOAD_LDS16(bSrc0 + kk + 32, &Bs[lo + la0]);
            GLOAD_LDS16(bSrc1 + kk + 32, &Bs[lo + la1]);
        }
        __builtin_amdgcn_sched_barrier(0);

        const int lo = cur * 4096;
        v8s af[4], bfr[4];
#pragma unroll
        for (int t = 0; t < 4; t++) {
            const int ra = wm + t * 16 + l16;
            af[t] = *(const v8s*)(&As[lo + ra * 32 + ((quad ^ ((ra >> 1) & 3)) * 8)]);
        }
#pragma unroll
        for (int t = 0; t < 4; t++) {
            const int rb = wn + t * 16 + l16;
            bfr[t] = *(const v8s*)(&Bs[lo + rb * 32 + ((quad ^ ((rb >> 1) & 3)) * 8)]);
        }
#pragma unroll
        for (int i = 0; i < 4; i++)
#pragma unroll
            for (int j = 0; j < 4; j++) acc[i][j] = MFMA(af[i], bfr[j], acc[i][j]);
        cur ^= 1;
    }

    if (mode == 2) {
        if (n0 < 2048) {
            __syncthreads();
            float* red = (float*)As;  // [128 rows][2 wn-halves]
#pragma unroll
            for (int i = 0; i < 4; i++) {
#pragma unroll
                for (int r = 0; r < 4; r++) {
                    float ss2 = 0.f;
#pragma unroll
                    for (int j = 0; j < 4; j++) { float v = acc[i][j][r]; ss2 += v * v; }
#pragma unroll
                    for (int off2 = 1; off2 < 16; off2 <<= 1) ss2 += __shfl_xor(ss2, off2);
                    if (l16 == 0) red[(wm + i * 16 + quad * 4 + r) * 2 + (wn >> 6)] = ss2;
                }
            }
            __syncthreads();
            float gv[4];
#pragma unroll
            for (int j = 0; j < 4; j++) gv[j] = g[wn + j * 16 + l16];
#pragma unroll
            for (int i = 0; i < 4; i++) {
#pragma unroll
                for (int r = 0; r < 4; r++) {
                    const int rl = wm + i * 16 + quad * 4 + r;
                    const float rs =
                        rsqrtf((red[rl * 2] + red[rl * 2 + 1]) * (1.f / 128.f) + 1e-6f) * scale;
#pragma unroll
                    for (int j = 0; j < 4; j++)
                        ((short*)C0)[(size_t)(m0 + rl) * 2048 + n0 + wn + j * 16 + l16] =
                            f2bs(acc[i][j][r] * rs * gv[j]);
                }
            }
        } else {
#pragma unroll
            for (int i = 0; i < 4; i++)
#pragma unroll
                for (int r = 0; r < 4; r++) {
                    const int row = m0 + wm + i * 16 + quad * 4 + r;
#pragma unroll
                    for (int j = 0; j < 4; j++)
                        ((short*)C1)[(size_t)row * 512 + n0 - 2048 + wn + j * 16 + l16] =
                            f2bs(acc[i][j][r]);
                }
        }
        return;
    }

    if (mode == 3 && n0 >= 2048) {
        // V epilogue -> packed Vp[bh][kt][d][key]; 4 consecutive tokens per 8B store
        short* C = (short*)C2;
#pragma unroll
        for (int i = 0; i < 4; i++) {
            const int row = m0 + wm + i * 16 + quad * 4;  // token (r=0 base)
            const int bq = row >> 11, s = row & 2047;
            const int kt = s >> 6, key = s & 63;
#pragma unroll
            for (int j = 0; j < 4; j++) {
                const int col = n0 - 2048 + wn + j * 16 + l16;  // h*128+d
                const int hh = col >> 7, d = col & 127;
                size_t base = ((size_t)((bq * 16 + hh) * 32 + kt) * 128 + d) * 64 + key;
                short pk[4];
#pragma unroll
                for (int r = 0; r < 4; r++) pk[r] = f2bs(acc[i][j][r]);
                *(uint2*)(C + base) = *(const uint2*)pk;
            }
        }
        return;
    }

    void* Cb = C0;
    int ld = N, coff = 0;
    if (mode == 3) {
        if (n0 < 1024) { Cb = C0; ld = 1024; coff = 0; }
        else           { Cb = C1; ld = 1024; coff = 1024; }
    }
#pragma unroll
    for (int i = 0; i < 4; i++) {
#pragma unroll
        for (int r = 0; r < 4; r++) {
            const int row = m0 + wm + i * 16 + quad * 4 + r;
#pragma unroll
            for (int j = 0; j < 4; j++) {
                const int col = n0 - coff + wn + j * 16 + l16;
                float v = acc[i][j][r];
                if (mode == 1) ((float*)Cb)[(size_t)row * ld + col] = v;
                else ((short*)Cb)[(size_t)row * ld + col] = f2bs(v);
            }
        }
    }
}

// ------------------------------------------------------------- RMSNorm (k)
__global__ __launch_bounds__(256) void rmsnorm_k(const short* __restrict__ KR,
                                                 const short* __restrict__ KN,
                                                 const float* __restrict__ g,
                                                 short* __restrict__ Y) {
    const int tid = threadIdx.x;
    const int rh = blockIdx.x * 32 + (tid >> 3);  // row = m*16+h
    const int j = tid & 7;                        // lane-in-row, 8 elems each
    const size_t ibase = (size_t)blockIdx.x * 2048 + (size_t)tid * 8;
    v8s a = *(const v8s*)(KR + ibase);
    v8s c = *(const v8s*)(KN + ibase);
    float af[8], cf[8];
    float ss = 0.f;
#pragma unroll
    for (int t = 0; t < 8; t++) {
        af[t] = bs2f(a[t]);
        cf[t] = bs2f(c[t]);
        ss += af[t] * af[t] + cf[t] * cf[t];
    }
#pragma unroll
    for (int off = 1; off < 8; off <<= 1) ss += __shfl_xor(ss, off);
    const float rs = rsqrtf(ss * (1.f / 128.f) + 1e-6f);
    const int m = rh >> 4, h = rh & 15;
    const int b = m >> 11, s = m & 2047;
    const size_t obase = ((size_t)((b * 16 + h) * 32 + (s >> 6)) * 64 + (s & 63)) * 128;
    const float* gp = g + j * 8;
    v8s o0, o1;
#pragma unroll
    for (int t = 0; t < 8; t++) {
        o0[t] = f2bs(af[t] * rs * gp[t]);
        o1[t] = f2bs(cf[t] * rs * gp[64 + t]);
    }
    *(v8s*)(Y + obase + j * 8) = o0;
    *(v8s*)(Y + obase + 64 + j * 8) = o1;
}

// ------------------------------------------------------ flash attention (causal)
// v5: 32x32x16 MFMA restructure. 1024 blocks x 4 waves, 64 q-rows/block.
// Wave w: q-group qg=w&1 (32 rows at qb*64+qg*32), KEY-group kg=w>>1
// (keys kg*32..+31 of every tile). Static-shift softmax => the two key-group
// partials per q-group are ADDITIVE; one f32 LDS combine at the end.
// All 4 waves active every tile; per-block LDS-read bytes halved vs v3
// (each wave reads 8KB K + 8KB V per tile for 32 q-rows).
// SWAPPED QK^T at 32x32: S^T = mfma(A=K, B=Q): C col = lane&31 = q (verified
// m74/m101 layout: row key = (r&3)+8*(r>>2)+4*(lane>>5)) -> each lane holds
// its q's P-row segment IN REGISTERS. P -> PV A-frag (row=lane&31=q,
// k=(lane>>5)*8+j) is register-only: pack bf16 pairs + one shfl_xor(32)
// half-exchange per 16-key chunk (reg r = (j&3)+8*kcl+4*h_dest). Ps LDS
// buffer DELETED -> kills the C->A round-trip bank conflicts (5.9M cyc).
// L via per-lane f32 sum + shfl_xor(32) (covers the lane's key mod-8 half).
// Staging (GLOAD pattern, XOR swizzles), grid, heavy-first order: = v3.
// LDS 33KB; launch_bounds(256,3) caps VGPR ~170 -> 12 waves/CU = 3 blocks/CU.
__global__ __launch_bounds__(256, 3) void flash_attn(const short* __restrict__ Q,
                                                     const short* __restrict__ Kp,
                                                     const short* __restrict__ Vp,
                                                     short* __restrict__ O, int S) {
    __shared__ short Ks[64 * 128];   // [key][d], rows 256B, XOR-swizzled
    __shared__ short Vs[128 * 64];   // [d][key], rows 128B, XOR-swizzled
    __shared__ float Lb[64];

    const int lane = threadIdx.x & 63, w = threadIdx.x >> 6;
    const int l32 = lane & 31, hl = lane >> 5, l8 = lane & 7;
    const int qg = w & 1, kg = w >> 1;
    const int blk = blockIdx.x;
    const int g = blk >> 3;                    // 0..127
    const int bh = (blk & 7) * 4 + (g & 3);    // same-bh -> same XCD (L2 reuse)
    const int b = bh >> 4, hd = bh & 15;
    const int qb = 31 - (g >> 2);              // heavy blocks first
    const int q0w = qb * 64 + qg * 32;         // this wave's 32 q-rows

    // staging offsets (verbatim v3; involution byte ^= ((row&7)<<4))
    const int koffE = (lane >> 4) * 128 + (((lane & 15) ^ (lane >> 4)) << 3);
    const int koffO = (lane >> 4) * 128 + (((lane & 15) ^ 4 ^ (lane >> 4)) << 3);
    const int voffc = (lane >> 3) * 64 + (((lane & 7) ^ (lane >> 3)) << 3);

    // Q fragments (B-operand 32x32x16): col q = l32, k(d) = hl*8+j per chunk dc
    v8s bq[8];
    {
        const size_t qbase = ((size_t)(b * S + q0w + l32) * 16 + hd) * 128;
#pragma unroll
        for (int dc = 0; dc < 8; dc++)
            bq[dc] = *(const v8s*)(Q + qbase + dc * 16 + hl * 8);
    }

    v16f accO[4];
#pragma unroll
    for (int dg = 0; dg < 4; dg++)
#pragma unroll
        for (int i = 0; i < 16; i++) accO[dg][i] = 0.f;
    float Lacc = 0.f;

    const short* const kbh = Kp + (size_t)(bh * 32) * 8192;  // + kt*8192
    const short* const vbh = Vp + (size_t)(bh * 32) * 8192;
    const int c0 = w * 4;  // this wave's 4 K-chunks + 4 V-chunks (1KB each)

    const int nkt = qb + 1;  // 64-key tiles for this block
    for (int kt = 0; kt < nkt; ++kt) {
        __syncthreads();  // previous tile's LDS reads done before overwrite
        {
            const short* kb = kbh + (size_t)kt * 8192;
            const short* vb = vbh + (size_t)kt * 8192;
            GLOAD_LDS16(kb + (c0 + 0) * 512 + koffE, Ks + (c0 + 0) * 512);
            GLOAD_LDS16(kb + (c0 + 1) * 512 + koffO, Ks + (c0 + 1) * 512);
            GLOAD_LDS16(kb + (c0 + 2) * 512 + koffE, Ks + (c0 + 2) * 512);
            GLOAD_LDS16(kb + (c0 + 3) * 512 + koffO, Ks + (c0 + 3) * 512);
            GLOAD_LDS16(vb + (c0 + 0) * 512 + voffc, Vs + (c0 + 0) * 512);
            GLOAD_LDS16(vb + (c0 + 1) * 512 + voffc, Vs + (c0 + 1) * 512);
            GLOAD_LDS16(vb + (c0 + 2) * 512 + voffc, Vs + (c0 + 2) * 512);
            GLOAD_LDS16(vb + (c0 + 3) * 512 + voffc, Vs + (c0 + 3) * 512);
        }
        __syncthreads();  // staging complete (barrier drains vmcnt)

        // S^T (32 keys x 32 q) = mfma32(A=K, B=Q), chained over 8 d-chunks
        v16f acc2;
#pragma unroll
        for (int i = 0; i < 16; i++) acc2[i] = 0.f;
        __builtin_amdgcn_s_setprio(1);
#pragma unroll
        for (int dc = 0; dc < 8; dc++) {
            const int row = kg * 32 + l32;  // key row
            const v8s ak =
                *(const v8s*)(Ks + row * 128 + ((dc * 16 + hl * 8) ^ (l8 << 3)));
            acc2 = MFMA32(ak, bq[dc], acc2);
        }
        __builtin_amdgcn_s_setprio(0);

        // causal mask (diagonal tile only) + static-shift softmax p = 2^(s-20)
        float p[16];
        const int qglob = q0w + l32;
        const int kbase = kt * 64 + kg * 32 + 4 * hl;
#pragma unroll
        for (int r = 0; r < 16; r++) {
            float s = acc2[r];
            if (kt == nkt - 1) {
                const int key = kbase + (r & 3) + 8 * (r >> 2);
                if (key > qglob) s = -1e30f;
            }
            const float pv = exp2f(s - 20.f);
            p[r] = pv;
            Lacc += pv;
        }

        // P (regs) -> A-frags (row=q=l32, k=hl*8+j) via pack + half-exchange;
        // source reg for dest (kcl,h,j): r = (j&3) + 8*kcl + 4*h.
#pragma unroll
        for (int kcl = 0; kcl < 2; kcl++) {
            const int rb = kcl * 8;
            const unsigned qL0 = pkbf(p[rb + 0], p[rb + 1]);
            const unsigned qL1 = pkbf(p[rb + 2], p[rb + 3]);
            const unsigned qH0 = pkbf(p[rb + 4], p[rb + 5]);
            const unsigned qH1 = pkbf(p[rb + 6], p[rb + 7]);
            // send the quad the OTHER half needs; receive partner's
            const unsigned s0 = hl ? qL0 : qH0;
            const unsigned s1 = hl ? qL1 : qH1;
            const unsigned r0 = (unsigned)__shfl_xor((int)s0, 32);
            const unsigned r1 = (unsigned)__shfl_xor((int)s1, 32);
            int4 fi = {(int)(hl ? r0 : qL0), (int)(hl ? r1 : qL1),
                       (int)(hl ? qH0 : r0), (int)(hl ? qH1 : r1)};
            const v8s pa = *(const v8s*)&fi;

            __builtin_amdgcn_s_setprio(1);
#pragma unroll
            for (int dg = 0; dg < 4; dg++) {
                const int d = dg * 32 + l32;
                const v8s bv = *(const v8s*)(
                    Vs + d * 64 + (((kg * 2 + kcl) * 16 + hl * 8) ^ (l8 << 3)));
                accO[dg] = MFMA32(pa, bv, accO[dg]);
            }
            __builtin_amdgcn_s_setprio(0);
        }
    }

    // L over this wave's keys: lane covers key mod-8 half 4*hl..4*hl+3
    const float Ltot = Lacc + __shfl_xor(Lacc, 32);

    // combine key-group partials (f32) via LDS; qg=0 -> Ks, qg=1 -> Vs (16KB each)
    __syncthreads();
    float* dump = (float*)(qg == 0 ? (void*)Ks : (void*)Vs);
    if (kg) {
#pragma unroll
        for (int dg = 0; dg < 4; dg++)
#pragma unroll
            for (int r = 0; r < 16; r++) {
                const int rowidx = (r & 3) + 8 * (r >> 2) + 4 * hl;  // q 0..31
                dump[(dg * 32 + rowidx) * 32 + l32] = accO[dg][r];
            }
        if (hl == 0) Lb[qg * 32 + l32] = Ltot;
    }
    __syncthreads();
    if (!kg) {
        const float Lq = Ltot + Lb[qg * 32 + l32];  // L[q = l32], full keys
#pragma unroll
        for (int r = 0; r < 16; r++) {
            const int rowidx = (r & 3) + 8 * (r >> 2) + 4 * hl;
            const float inv = 1.f / __shfl(Lq, rowidx);
            const size_t obase =
                ((size_t)(b * S + qb * 64 + qg * 32 + rowidx) * 16 + hd) * 128;
#pragma unroll
            for (int dg = 0; dg < 4; dg++) {
                const float v = accO[dg][r] + dump[(dg * 32 + rowidx) * 32 + l32];
                O[obase + dg * 32 + l32] = f2bs(v * inv);
            }
        }
    }
}

// ---------------------------------------------------------------------------
extern "C" void kernel_launch(void* const* d_in, const int* in_sizes, int n_in,
                              void* d_out, int out_size, void* d_ws, size_t ws_size,
                              hipStream_t stream) {
    (void)in_sizes; (void)n_in; (void)out_size; (void)ws_size;
    const float* x   = (const float*)d_in[0];
    const float* Wq  = (const float*)d_in[1];
    const float* Wkv = (const float*)d_in[2];
    const float* Wkr = (const float*)d_in[3];
    const float* Wkn = (const float*)d_in[4];
    const float* Wv  = (const float*)d_in[5];
    const float* Wo  = (const float*)d_in[6];
    const float* gq  = (const float*)d_in[7];
    const float* gk  = (const float*)d_in[8];

    const int B = 2, S = 2048, HID = 2048;
    const int M = B * S;  // 4096

    char* ws = (char*)d_ws;
    size_t off = 0;
    auto alloc = [&](size_t bytes) {
        char* p = ws + off;
        off += (bytes + 255) & ~(size_t)255;
        return p;
    };
    short* xb   = (short*)alloc((size_t)M * HID * 2);
    short* WtA  = (short*)alloc((size_t)2560 * 2048 * 2);  // [Wq^T | Wkv^T]
    short* WtB  = (short*)alloc((size_t)4096 * 512 * 2);   // [Wkr^T | Wkn^T | Wv^T]
    short* Wot  = (short*)alloc((size_t)2048 * 2048 * 2);
    short* qb   = (short*)alloc((size_t)M * 2048 * 2);
    short* lat  = (short*)alloc((size_t)M * 512 * 2);
    short* krr  = (short*)alloc((size_t)M * 1024 * 2);
    short* knr  = (short*)alloc((size_t)M * 1024 * 2);
    short* Kp   = (short*)alloc((size_t)M * 2048 * 2);  // [bh][kt][key][d]
    short* Vp   = (short*)alloc((size_t)M * 2048 * 2);  // [bh][kt][d][key]
    short* ob   = (short*)alloc((size_t)M * 2048 * 2);

    // fused conversion + transposes (single launch)
    prep<<<19456, 256, 0, stream>>>(x, xb, Wq, Wkv, Wkr, Wkn, Wv, Wo, WtA, WtB, Wot);

    // GEMM-A: x @ [Wq | Wkv] -> qb (fused per-head RMSNorm, scale incl log2e) + lat
    gemm_bt<<<dim3(2560 / 128, M / 128), 256, 0, stream>>>(
        xb, WtA, qb, lat, nullptr, M, 2560, 2048, 2, gq,
        0.08838834764831845f * 1.4426950408889634f);

    // GEMM-B: lat @ [Wkr | Wkn | Wv] -> krr, knr, Vp(packed)
    gemm_bt<<<dim3(4096 / 128, M / 128), 256, 0, stream>>>(
        lat, WtB, krr, knr, Vp, M, 4096, 512, 3, nullptr, 0.f);
    rmsnorm_k<<<(M * 16) / 32, 256, 0, stream>>>(krr, knr, gk, Kp);

    // causal SDPA: 1024 blocks x 4 waves (q-group x key-group), 32x32 MFMA
    flash_attn<<<dim3(1024), 256, 0, stream>>>(qb, Kp, Vp, ob, S);

    // GEMM-C: out = o @ Wo (fp32)
    gemm_bt<<<dim3(2048 / 128, M / 128), 256, 0, stream>>>(
        ob, Wot, d_out, nullptr, nullptr, M, 2048, 2048, 1, nullptr, 0.f);
}

// Round 12
// 327.033 us; speedup vs baseline: 1.0220x; 1.0220x over previous
//
#include <hip/hip_runtime.h>
#include <cstdint>
#include <cstddef>

typedef short v8s __attribute__((ext_vector_type(8)));
typedef float v4f __attribute__((ext_vector_type(4)));

__device__ inline float bs2f(short s) {
    return __uint_as_float(((unsigned int)(unsigned short)s) << 16);
}
__device__ inline short f2bs(float f) {
    unsigned int u = __float_as_uint(f);
    unsigned int r = (u + 0x7fffu + ((u >> 16) & 1u)) >> 16;  // RNE
    return (short)r;
}

#define MFMA(a, b, c) __builtin_amdgcn_mfma_f32_16x16x32_bf16((a), (b), (c), 0, 0, 0)

// async global->LDS, 16B per lane, LDS dest = wave-uniform base + lane*16
#define GLOAD_LDS16(g, l)                                                  \
    __builtin_amdgcn_global_load_lds(                                      \
        (const __attribute__((address_space(1))) void*)(g),                \
        (__attribute__((address_space(3))) void*)(l), 16, 0, 0)

// ---------------------------------------------------- fused preprocessing
__global__ __launch_bounds__(256) void prep(const float* __restrict__ x,
                                            short* __restrict__ xb,
                                            const float* __restrict__ Wq,
                                            const float* __restrict__ Wkv,
                                            const float* __restrict__ Wkr,
                                            const float* __restrict__ Wkn,
                                            const float* __restrict__ Wv,
                                            const float* __restrict__ Wo,
                                            short* __restrict__ WtA,
                                            short* __restrict__ WtB,
                                            short* __restrict__ Wot) {
    int blk = blockIdx.x;
    if (blk < 8192) {
        int i = (blk * 256 + threadIdx.x) * 4;
        float4 v = *(const float4*)(x + i);
        short r[4] = {f2bs(v.x), f2bs(v.y), f2bs(v.z), f2bs(v.w)};
        *(uint2*)(xb + i) = *(const uint2*)r;
        return;
    }
    blk -= 8192;
    const float* W;
    short* Wt;
    int K, N, bx, by;
    if (blk < 4096)      { W = Wq;  Wt = WtA;                      K = 2048; N = 2048; bx = blk & 63; by = blk >> 6; }
    else if (blk < 5120) { blk -= 4096; W = Wkv; Wt = WtA + (size_t)2048 * 2048; K = 2048; N = 512;  bx = blk & 15; by = blk >> 4; }
    else if (blk < 5632) { blk -= 5120; W = Wkr; Wt = WtB;                       K = 512;  N = 1024; bx = blk & 31; by = blk >> 5; }
    else if (blk < 6144) { blk -= 5632; W = Wkn; Wt = WtB + (size_t)1024 * 512;  K = 512;  N = 1024; bx = blk & 31; by = blk >> 5; }
    else if (blk < 7168) { blk -= 6144; W = Wv;  Wt = WtB + (size_t)2048 * 512;  K = 512;  N = 2048; bx = blk & 63; by = blk >> 6; }
    else                 { blk -= 7168; W = Wo;  Wt = Wot;                       K = 2048; N = 2048; bx = blk & 63; by = blk >> 6; }

    __shared__ float tile[32][33];
    const int tx = threadIdx.x & 31, ty = threadIdx.x >> 5;  // ty 0..7
    const int n0 = bx * 32, k0 = by * 32;
#pragma unroll
    for (int i = 0; i < 32; i += 8) tile[ty + i][tx] = W[(size_t)(k0 + ty + i) * N + n0 + tx];
    __syncthreads();
#pragma unroll
    for (int i = 0; i < 32; i += 8)
        Wt[(size_t)(n0 + ty + i) * K + k0 + tx] = f2bs(tile[tx][ty + i]);
}

// ----------------------------------------------------------------- GEMM B^T
// 2-phase single-barrier double-buffer (the best-measured config).
__global__ __launch_bounds__(256) void gemm_bt(const short* __restrict__ A,
                                               const short* __restrict__ Bt,
                                               void* __restrict__ C0,
                                               void* __restrict__ C1,
                                               void* __restrict__ C2,
                                               int M, int N, int K, int mode,
                                               const float* __restrict__ g,
                                               float scale) {
    __shared__ short As[2 * 128 * 32];
    __shared__ short Bs[2 * 128 * 32];
    const int tid = threadIdx.x;
    const int lane = tid & 63, wave = tid >> 6;
    const int l16 = lane & 15, quad = lane >> 4;
    const int wm = (wave >> 1) * 64, wn = (wave & 1) * 64;

    const int gx = gridDim.x;
    const int nwg = gx * gridDim.y;
    const int wg = blockIdx.y * gx + blockIdx.x;
    const int cpx = nwg >> 3;
    const int swz = (wg & 7) * cpx + (wg >> 3);
    const int m0 = (swz / gx) * 128, n0 = (swz % gx) * 128;

    const v4f VZ = {0.f, 0.f, 0.f, 0.f};
    v4f acc[4][4];
#pragma unroll
    for (int i = 0; i < 4; i++)
#pragma unroll
        for (int j = 0; j < 4; j++) acc[i][j] = VZ;

    const int r0 = wave * 32 + (lane >> 2);
    const int r1 = r0 + 16;
    const int c0 = ((lane & 3) ^ ((r0 >> 1) & 3)) * 8;
    const int c1 = ((lane & 3) ^ ((r1 >> 1) & 3)) * 8;
    const short* aSrc0 = A + (size_t)(m0 + r0) * K + c0;
    const short* aSrc1 = A + (size_t)(m0 + r1) * K + c1;
    const short* bSrc0 = Bt + (size_t)(n0 + r0) * K + c0;
    const short* bSrc1 = Bt + (size_t)(n0 + r1) * K + c1;
    const int la0 = (wave * 32) * 32, la1 = (wave * 32 + 16) * 32;

    // prologue: stage tile 0 into buffer 0
    GLOAD_LDS16(aSrc0, &As[la0]);
    GLOAD_LDS16(aSrc1, &As[la1]);
    GLOAD_LDS16(bSrc0, &Bs[la0]);
    GLOAD_LDS16(bSrc1, &Bs[la1]);

    int cur = 0;
    for (int kk = 0; kk < K; kk += 32) {
        __syncthreads();  // buf[cur] staged (vmcnt drain) + prev reads done
        __builtin_amdgcn_sched_barrier(0);
        if (kk + 32 < K) {
            const int lo = (cur ^ 1) * 4096;
            GLOAD_LDS16(aSrc0 + kk + 32, &As[lo + la0]);
            GLOAD_LDS16(aSrc1 + kk + 32, &As[lo + la1]);
            GLOAD_LDS16(bSrc0 + kk + 32, &Bs[lo + la0]);
            GLOAD_LDS16(bSrc1 + kk + 32, &Bs[lo + la1]);
        }
        __builtin_amdgcn_sched_barrier(0);

        const int lo = cur * 4096;
        v8s af[4], bfr[4];
#pragma unroll
        for (int t = 0; t < 4; t++) {
            const int ra = wm + t * 16 + l16;
            af[t] = *(const v8s*)(&As[lo + ra * 32 + ((quad ^ ((ra >> 1) & 3)) * 8)]);
        }
#pragma unroll
        for (int t = 0; t < 4; t++) {
            const int rb = wn + t * 16 + l16;
            bfr[t] = *(const v8s*)(&Bs[lo + rb * 32 + ((quad ^ ((rb >> 1) & 3)) * 8)]);
        }
#pragma unroll
        for (int i = 0; i < 4; i++)
#pragma unroll
            for (int j = 0; j < 4; j++) acc[i][j] = MFMA(af[i], bfr[j], acc[i][j]);
        cur ^= 1;
    }

    if (mode == 2) {
        if (n0 < 2048) {
            __syncthreads();
            float* red = (float*)As;  // [128 rows][2 wn-halves]
#pragma unroll
            for (int i = 0; i < 4; i++) {
#pragma unroll
                for (int r = 0; r < 4; r++) {
                    float ss2 = 0.f;
#pragma unroll
                    for (int j = 0; j < 4; j++) { float v = acc[i][j][r]; ss2 += v * v; }
#pragma unroll
                    for (int off2 = 1; off2 < 16; off2 <<= 1) ss2 += __shfl_xor(ss2, off2);
                    if (l16 == 0) red[(wm + i * 16 + quad * 4 + r) * 2 + (wn >> 6)] = ss2;
                }
            }
            __syncthreads();
            float gv[4];
#pragma unroll
            for (int j = 0; j < 4; j++) gv[j] = g[wn + j * 16 + l16];
#pragma unroll
            for (int i = 0; i < 4; i++) {
#pragma unroll
                for (int r = 0; r < 4; r++) {
                    const int rl = wm + i * 16 + quad * 4 + r;
                    const float rs =
                        rsqrtf((red[rl * 2] + red[rl * 2 + 1]) * (1.f / 128.f) + 1e-6f) * scale;
#pragma unroll
                    for (int j = 0; j < 4; j++)
                        ((short*)C0)[(size_t)(m0 + rl) * 2048 + n0 + wn + j * 16 + l16] =
                            f2bs(acc[i][j][r] * rs * gv[j]);
                }
            }
        } else {
#pragma unroll
            for (int i = 0; i < 4; i++)
#pragma unroll
                for (int r = 0; r < 4; r++) {
                    const int row = m0 + wm + i * 16 + quad * 4 + r;
#pragma unroll
                    for (int j = 0; j < 4; j++)
                        ((short*)C1)[(size_t)row * 512 + n0 - 2048 + wn + j * 16 + l16] =
                            f2bs(acc[i][j][r]);
                }
        }
        return;
    }

    if (mode == 3 && n0 >= 2048) {
        // V epilogue -> packed Vp[bh][kt][d][key]; 4 consecutive tokens per 8B store
        short* C = (short*)C2;
#pragma unroll
        for (int i = 0; i < 4; i++) {
            const int row = m0 + wm + i * 16 + quad * 4;  // token (r=0 base)
            const int bq = row >> 11, s = row & 2047;
            const int kt = s >> 6, key = s & 63;
#pragma unroll
            for (int j = 0; j < 4; j++) {
                const int col = n0 - 2048 + wn + j * 16 + l16;  // h*128+d
                const int hh = col >> 7, d = col & 127;
                size_t base = ((size_t)((bq * 16 + hh) * 32 + kt) * 128 + d) * 64 + key;
                short pk[4];
#pragma unroll
                for (int r = 0; r < 4; r++) pk[r] = f2bs(acc[i][j][r]);
                *(uint2*)(C + base) = *(const uint2*)pk;
            }
        }
        return;
    }

    void* Cb = C0;
    int ld = N, coff = 0;
    if (mode == 3) {
        if (n0 < 1024) { Cb = C0; ld = 1024; coff = 0; }
        else           { Cb = C1; ld = 1024; coff = 1024; }
    }
#pragma unroll
    for (int i = 0; i < 4; i++) {
#pragma unroll
        for (int r = 0; r < 4; r++) {
            const int row = m0 + wm + i * 16 + quad * 4 + r;
#pragma unroll
            for (int j = 0; j < 4; j++) {
                const int col = n0 - coff + wn + j * 16 + l16;
                float v = acc[i][j][r];
                if (mode == 1) ((float*)Cb)[(size_t)row * ld + col] = v;
                else ((short*)Cb)[(size_t)row * ld + col] = f2bs(v);
            }
        }
    }
}

// ------------------------------------------------------------- RMSNorm (k)
__global__ __launch_bounds__(256) void rmsnorm_k(const short* __restrict__ KR,
                                                 const short* __restrict__ KN,
                                                 const float* __restrict__ g,
                                                 short* __restrict__ Y) {
    const int tid = threadIdx.x;
    const int rh = blockIdx.x * 32 + (tid >> 3);  // row = m*16+h
    const int j = tid & 7;                        // lane-in-row, 8 elems each
    const size_t ibase = (size_t)blockIdx.x * 2048 + (size_t)tid * 8;
    v8s a = *(const v8s*)(KR + ibase);
    v8s c = *(const v8s*)(KN + ibase);
    float af[8], cf[8];
    float ss = 0.f;
#pragma unroll
    for (int t = 0; t < 8; t++) {
        af[t] = bs2f(a[t]);
        cf[t] = bs2f(c[t]);
        ss += af[t] * af[t] + cf[t] * cf[t];
    }
#pragma unroll
    for (int off = 1; off < 8; off <<= 1) ss += __shfl_xor(ss, off);
    const float rs = rsqrtf(ss * (1.f / 128.f) + 1e-6f);
    const int m = rh >> 4, h = rh & 15;
    const int b = m >> 11, s = m & 2047;
    const size_t obase = ((size_t)((b * 16 + h) * 32 + (s >> 6)) * 64 + (s & 63)) * 128;
    const float* gp = g + j * 8;
    v8s o0, o1;
#pragma unroll
    for (int t = 0; t < 8; t++) {
        o0[t] = f2bs(af[t] * rs * gp[t]);
        o1[t] = f2bs(cf[t] * rs * gp[64 + t]);
    }
    *(v8s*)(Y + obase + j * 8) = o0;
    *(v8s*)(Y + obase + 64 + j * 8) = o1;
}

// ------------------------------------------------------ flash attention (causal)
// v4 (the 329.07us-measured config): 1024 blocks x 4 waves, 64 q-rows/block,
// 2-phase single-barrier K/V double-buffer, T5 setprio, XOR-swizzled LDS.
#define PSTR 72   // Ps [qrow][key] row stride in shorts

__global__ __launch_bounds__(256) void flash_attn(const short* __restrict__ Q,
                                                  const short* __restrict__ Kp,
                                                  const short* __restrict__ Vp,
                                                  short* __restrict__ O, int S) {
    __shared__ short Ks[2][64 * 128];   // [key][d], rows 256B, XOR-swizzled
    __shared__ short Vs[2][128 * 64];   // [d][key], rows 128B, XOR-swizzled
    __shared__ short Ps[4][16 * PSTR];

    const int lane = threadIdx.x & 63, w = threadIdx.x >> 6;
    const int l16 = lane & 15, quad = lane >> 4;
    const int blk = blockIdx.x;
    const int g = blk >> 3;                    // 0..127
    const int bh = (blk & 7) * 4 + (g & 3);    // same-bh -> same XCD (L2 reuse)
    const int b = bh >> 4, h = bh & 15;
    const int qb = 31 - (g >> 2);              // heavy blocks first
    const int q0 = qb * 64 + w * 16;           // this wave's 16 q-rows

    const int koffE = (lane >> 4) * 128 + (((lane & 15) ^ (lane >> 4)) << 3);
    const int koffO = (lane >> 4) * 128 + (((lane & 15) ^ 4 ^ (lane >> 4)) << 3);
    const int voffc = (lane >> 3) * 64 + (((lane & 7) ^ (lane >> 3)) << 3);
    const int swz = (l16 & 7) * 8;             // ds_read-side XOR (shorts)

    const short* const kbh = Kp + (size_t)(bh * 32) * 8192;  // + kt*8192
    const short* const vbh = Vp + (size_t)(bh * 32) * 8192;
    const int c0 = w * 4;  // this wave's 4 K-chunks + 4 V-chunks (1KB each)

    // Q fragments (B-operand): lane l16 = q-col, quad*8.. = d
    v8s bq[4];
    {
        const size_t qbase = ((size_t)(b * S + q0 + l16) * 16 + h) * 128;
#pragma unroll
        for (int kc = 0; kc < 4; kc++)
            bq[kc] = *(const v8s*)(Q + qbase + kc * 32 + quad * 8);
    }

    const v4f VZ = {0.f, 0.f, 0.f, 0.f};
    v4f accO[8];
    v4f accL = VZ;
#pragma unroll
    for (int d = 0; d < 8; d++) accO[d] = VZ;

    const short o1 = 0x3F80;  // bf16 1.0
    const v8s vones = {o1, o1, o1, o1, o1, o1, o1, o1};

    const int nkt = qb + 1;  // 64-key tiles for this block

    // prologue: stage tile 0 into buffer 0
    {
        const short* kb = kbh;
        const short* vb = vbh;
        GLOAD_LDS16(kb + (c0 + 0) * 512 + koffE, &Ks[0][(c0 + 0) * 512]);
        GLOAD_LDS16(kb + (c0 + 1) * 512 + koffO, &Ks[0][(c0 + 1) * 512]);
        GLOAD_LDS16(kb + (c0 + 2) * 512 + koffE, &Ks[0][(c0 + 2) * 512]);
        GLOAD_LDS16(kb + (c0 + 3) * 512 + koffO, &Ks[0][(c0 + 3) * 512]);
        GLOAD_LDS16(vb + (c0 + 0) * 512 + voffc, &Vs[0][(c0 + 0) * 512]);
        GLOAD_LDS16(vb + (c0 + 1) * 512 + voffc, &Vs[0][(c0 + 1) * 512]);
        GLOAD_LDS16(vb + (c0 + 2) * 512 + voffc, &Vs[0][(c0 + 2) * 512]);
        GLOAD_LDS16(vb + (c0 + 3) * 512 + voffc, &Vs[0][(c0 + 3) * 512]);
    }

    int cur = 0;
    for (int kt = 0; kt < nkt; ++kt) {
        __syncthreads();  // buf[cur] staged (vmcnt drain) + prev reads of buf[cur^1] done
        __builtin_amdgcn_sched_barrier(0);
        if (kt + 1 < nkt) {
            const short* kb = kbh + (size_t)(kt + 1) * 8192;
            const short* vb = vbh + (size_t)(kt + 1) * 8192;
            short* ksd = &Ks[cur ^ 1][0];
            short* vsd = &Vs[cur ^ 1][0];
            GLOAD_LDS16(kb + (c0 + 0) * 512 + koffE, ksd + (c0 + 0) * 512);
            GLOAD_LDS16(kb + (c0 + 1) * 512 + koffO, ksd + (c0 + 1) * 512);
            GLOAD_LDS16(kb + (c0 + 2) * 512 + koffE, ksd + (c0 + 2) * 512);
            GLOAD_LDS16(kb + (c0 + 3) * 512 + koffO, ksd + (c0 + 3) * 512);
            GLOAD_LDS16(vb + (c0 + 0) * 512 + voffc, vsd + (c0 + 0) * 512);
            GLOAD_LDS16(vb + (c0 + 1) * 512 + voffc, vsd + (c0 + 1) * 512);
            GLOAD_LDS16(vb + (c0 + 2) * 512 + voffc, vsd + (c0 + 2) * 512);
            GLOAD_LDS16(vb + (c0 + 3) * 512 + voffc, vsd + (c0 + 3) * 512);
        }
        __builtin_amdgcn_sched_barrier(0);

        const short* const ksr = &Ks[cur][0];
        const short* const vsr = &Vs[cur][0];

        // S^T tile = K Q^T: rows = keys (quad*4+r), cols = q (l16)
        v4f sc[4];
        __builtin_amdgcn_s_setprio(1);
#pragma unroll
        for (int nt = 0; nt < 4; nt++) {
            v8s ak[4];
            const int krow = (nt * 16 + l16) * 128;
#pragma unroll
            for (int kc = 0; kc < 4; kc++)
                ak[kc] = *(const v8s*)(ksr + krow + ((quad * 8 + kc * 32) ^ swz));
            v4f s = VZ;
#pragma unroll
            for (int kc = 0; kc < 4; kc++) s = MFMA(ak[kc], bq[kc], s);
            sc[nt] = s;
        }
        __builtin_amdgcn_s_setprio(0);

        // causal mask: only the diagonal tile
        if (kt == nkt - 1) {
            const int qrow = q0 + l16;
            const int k0 = kt * 64;
#pragma unroll
            for (int nt = 0; nt < 4; nt++)
#pragma unroll
                for (int r = 0; r < 4; r++)
                    if (k0 + nt * 16 + quad * 4 + r > qrow) sc[nt][r] = -1e30f;
        }

        // static-shift softmax numerator: p = 2^(s - 20)
#pragma unroll
        for (int nt = 0; nt < 4; nt++) {
            short pk[4];
#pragma unroll
            for (int r = 0; r < 4; r++) {
                float p = exp2f(sc[nt][r] - 20.f);
                pk[r] = (short)(__float_as_uint(p) >> 16);  // truncating bf16
            }
            *(uint2*)(&Ps[w][l16 * PSTR + nt * 16 + quad * 4]) = *(const uint2*)pk;
        }

        // O += P V ; L += P 1  (P: A-layout from wave-private LDS)
        v8s ap[2];
#pragma unroll
        for (int kc2 = 0; kc2 < 2; kc2++)
            ap[kc2] = *(const v8s*)(&Ps[w][l16 * PSTR + kc2 * 32 + quad * 8]);
        __builtin_amdgcn_s_setprio(1);
#pragma unroll
        for (int dt = 0; dt < 8; dt++) {
            const int vrow = (dt * 16 + l16) * 64;
#pragma unroll
            for (int kc2 = 0; kc2 < 2; kc2++) {
                v8s bv = *(const v8s*)(vsr + vrow + ((quad * 8 + kc2 * 32) ^ swz));
                accO[dt] = MFMA(ap[kc2], bv, accO[dt]);
            }
        }
#pragma unroll
        for (int kc2 = 0; kc2 < 2; kc2++) accL = MFMA(ap[kc2], vones, accL);
        __builtin_amdgcn_s_setprio(0);
        cur ^= 1;
    }

    // epilogue: each wave owns its 16 q-rows outright (no combine)
#pragma unroll
    for (int r = 0; r < 4; r++) {
        const int rl = quad * 4 + r;  // q-row within wave's 16
        const int qg = q0 + rl;
        const float inv = 1.f / accL[r];
        const size_t obase = ((size_t)(b * S + qg) * 16 + h) * 128;
#pragma unroll
        for (int dt = 0; dt < 8; dt++)
            O[obase + dt * 16 + l16] = f2bs(accO[dt][r] * inv);
    }
}

// ---------------------------------------------------------------------------
extern "C" void kernel_launch(void* const* d_in, const int* in_sizes, int n_in,
                              void* d_out, int out_size, void* d_ws, size_t ws_size,
                              hipStream_t stream) {
    (void)in_sizes; (void)n_in; (void)out_size; (void)ws_size;
    const float* x   = (const float*)d_in[0];
    const float* Wq  = (const float*)d_in[1];
    const float* Wkv = (const float*)d_in[2];
    const float* Wkr = (const float*)d_in[3];
    const float* Wkn = (const float*)d_in[4];
    const float* Wv  = (const float*)d_in[5];
    const float* Wo  = (const float*)d_in[6];
    const float* gq  = (const float*)d_in[7];
    const float* gk  = (const float*)d_in[8];

    const int B = 2, S = 2048, HID = 2048;
    const int M = B * S;  // 4096

    char* ws = (char*)d_ws;
    size_t off = 0;
    auto alloc = [&](size_t bytes) {
        char* p = ws + off;
        off += (bytes + 255) & ~(size_t)255;
        return p;
    };
    short* xb   = (short*)alloc((size_t)M * HID * 2);
    short* WtA  = (short*)alloc((size_t)2560 * 2048 * 2);  // [Wq^T | Wkv^T]
    short* WtB  = (short*)alloc((size_t)4096 * 512 * 2);   // [Wkr^T | Wkn^T | Wv^T]
    short* Wot  = (short*)alloc((size_t)2048 * 2048 * 2);
    short* qb   = (short*)alloc((size_t)M * 2048 * 2);
    short* lat  = (short*)alloc((size_t)M * 512 * 2);
    short* krr  = (short*)alloc((size_t)M * 1024 * 2);
    short* knr  = (short*)alloc((size_t)M * 1024 * 2);
    short* Kp   = (short*)alloc((size_t)M * 2048 * 2);  // [bh][kt][key][d]
    short* Vp   = (short*)alloc((size_t)M * 2048 * 2);  // [bh][kt][d][key]
    short* ob   = (short*)alloc((size_t)M * 2048 * 2);

    // fused conversion + transposes (single launch)
    prep<<<19456, 256, 0, stream>>>(x, xb, Wq, Wkv, Wkr, Wkn, Wv, Wo, WtA, WtB, Wot);

    // GEMM-A: x @ [Wq | Wkv] -> qb (fused per-head RMSNorm, scale incl log2e) + lat
    gemm_bt<<<dim3(2560 / 128, M / 128), 256, 0, stream>>>(
        xb, WtA, qb, lat, nullptr, M, 2560, 2048, 2, gq,
        0.08838834764831845f * 1.4426950408889634f);

    // GEMM-B: lat @ [Wkr | Wkn | Wv] -> krr, knr, Vp(packed)
    gemm_bt<<<dim3(4096 / 128, M / 128), 256, 0, stream>>>(
        lat, WtB, krr, knr, Vp, M, 4096, 512, 3, nullptr, 0.f);
    rmsnorm_k<<<(M * 16) / 32, 256, 0, stream>>>(krr, knr, gk, Kp);

    // causal SDPA: 1024 blocks x 4 waves, 64 q-rows/block, dbuf LDS K/V
    flash_attn<<<dim3(1024), 256, 0, stream>>>(qb, Kp, Vp, ob, S);

    // GEMM-C: out = o @ Wo (fp32)
    gemm_bt<<<dim3(2048 / 128, M / 128), 256, 0, stream>>>(
        ob, Wot, d_out, nullptr, nullptr, M, 2048, 2048, 1, nullptr, 0.f);
}